// Round 7
// baseline (136.559 us; speedup 1.0000x reference)
//
#include <hip/hip_runtime.h>

#define N_NODES 100000
#define N_EDGES 600000
#define N_PAD   100352      // N_NODES rounded to 1024 (scan tiles)
#define NB1     98          // N_PAD / 1024
#define G1_WAVES 6250       // N_NODES / 16 exactly
#define G1_BLOCKS 1563      // ceil(6250/4)
#define HIST_BLOCKS 2344    // ceil(600000/256)
#define MID_BLOCKS 3125     // N_NODES / 32 exactly

typedef __bf16 bf16x8 __attribute__((ext_vector_type(8)));
typedef float  f32x4  __attribute__((ext_vector_type(4)));
typedef unsigned short u16x8 __attribute__((ext_vector_type(8)));
typedef unsigned short u16x4 __attribute__((ext_vector_type(4)));

__device__ inline unsigned short f2bf(float f) {
    __bf16 h = (__bf16)f;
    return __builtin_bit_cast(unsigned short, h);
}
__device__ inline float bf2f(unsigned short u) {
    return __builtin_bit_cast(float, ((unsigned)u) << 16);
}
__device__ inline bf16x8 ldfrag_bf16(const unsigned short* p) {
    u16x8 v = *(const u16x8*)p;
    return __builtin_bit_cast(bf16x8, v);
}
__device__ inline bf16x8 cvt_pair(float4 u, float4 w) {
    u16x8 o;
    o[0]=f2bf(u.x); o[1]=f2bf(u.y); o[2]=f2bf(u.z); o[3]=f2bf(u.w);
    o[4]=f2bf(w.x); o[5]=f2bf(w.y); o[6]=f2bf(w.z); o[7]=f2bf(w.w);
    return __builtin_bit_cast(bf16x8, o);
}

// ---------------------------------------------------------------------------
// prep: zero deg + gbase, convert W1 ([128][128]) and W2 ([64][64]) to bf16
// ---------------------------------------------------------------------------
__global__ __launch_bounds__(256) void prep(
    const float* __restrict__ w1l, const float* __restrict__ w1r,
    const float* __restrict__ w2l, const float* __restrict__ w2r,
    unsigned short* __restrict__ wbf1, unsigned short* __restrict__ wbf2,
    int* __restrict__ deg, int* __restrict__ gbase)
{
    int i = blockIdx.x * 256 + threadIdx.x;
    if (i < N_PAD) deg[i] = 0;
    if (i == 0) gbase[0] = 0;
    if (i < 16384) {
        int row = i >> 7, k = i & 127;
        float v = (row < 64) ? w1l[(row << 7) + k] : w1r[((row - 64) << 7) + k];
        wbf1[i] = f2bf(v);
    } else if (i < 20480) {
        int j = i - 16384;
        int row = j >> 6, k = j & 63;
        float v = (row < 32) ? w2l[(row << 6) + k] : w2r[((row - 32) << 6) + k];
        wbf2[j] = f2bf(v);
    }
}

// ---------------------------------------------------------------------------
// front: blocks [0,G1_BLOCKS) = layer-1 GEMM (16 nodes/wave, swapped MFMA,
//        ALL x loads preissued -> one latency round-trip);
//        blocks [G1_BLOCKS, +HIST_BLOCKS) = degree histogram.
// ---------------------------------------------------------------------------
__global__ __launch_bounds__(256) void front(
    const float* __restrict__ x,
    const unsigned short* __restrict__ wbf1,   // [128][128] bf16
    const int* __restrict__ ei,
    unsigned short* __restrict__ xl,
    unsigned short* __restrict__ xr,
    int* __restrict__ deg)
{
    const int b   = blockIdx.x;
    const int tid = threadIdx.x;

    if (b >= G1_BLOCKS) {
        int e = (b - G1_BLOCKS) * 256 + tid;
        if (e < N_EDGES) atomicAdd(&deg[ei[N_EDGES + e]], 1);
        return;
    }

    const int wid = b * 4 + (tid >> 6);
    if (wid >= G1_WAVES) return;
    const int l    = tid & 63;
    const int lrow = l & 15;
    const int hi   = l >> 4;
    const int node = wid * 16 + lrow;          // < 100000 always

    // ---- preload the lane's entire x slice: 8 independent dwordx4 ----
    const float* xp = x + node * 128 + hi * 8;
    float4 xa[8];
    #pragma unroll
    for (int kt = 0; kt < 4; ++kt) {
        xa[2 * kt]     = *(const float4*)(xp + kt * 32);
        xa[2 * kt + 1] = *(const float4*)(xp + kt * 32 + 4);
    }

    f32x4 acc[8];
    #pragma unroll
    for (int mt = 0; mt < 8; ++mt) acc[mt] = (f32x4){0.f,0.f,0.f,0.f};

    #pragma unroll
    for (int kt = 0; kt < 4; ++kt) {
        const int kc = kt * 32 + hi * 8;
        bf16x8 bfrag = cvt_pair(xa[2 * kt], xa[2 * kt + 1]);
        #pragma unroll
        for (int mt = 0; mt < 8; ++mt) {
            bf16x8 a = ldfrag_bf16(wbf1 + (mt * 16 + lrow) * 128 + kc);  // L1-resident
            acc[mt] = __builtin_amdgcn_mfma_f32_16x16x32_bf16(a, bfrag, acc[mt], 0, 0, 0);
        }
    }

    // D: col = lane&15 -> node, row = hi*4 + r -> feat
    const int fgrp = hi * 4;
    #pragma unroll
    for (int mt = 0; mt < 8; ++mt) {
        u16x4 p;
        p[0] = f2bf(acc[mt][0]); p[1] = f2bf(acc[mt][1]);
        p[2] = f2bf(acc[mt][2]); p[3] = f2bf(acc[mt][3]);
        const int feat = mt * 16 + fgrp;
        if (mt < 4) *(u16x4*)&xl[node * 64 + feat]        = p;
        else        *(u16x4*)&xr[node * 64 + (feat - 64)] = p;
    }
}

// ---------------------------------------------------------------------------
// scan: per-block scan of deg + atomic global base -> start[], cursor[]
// ---------------------------------------------------------------------------
__global__ __launch_bounds__(256) void scan_atomic(
    const int* __restrict__ deg, int* __restrict__ gbase,
    int* __restrict__ start, int* __restrict__ cursor)
{
    __shared__ int s[256];
    __shared__ int base_s;
    int b = blockIdx.x, tid = threadIdx.x;
    int i = b * 1024 + tid * 4;
    int4 v = *(const int4*)&deg[i];
    int p0 = v.x, p1 = p0 + v.y, p2 = p1 + v.z, p3 = p2 + v.w;
    s[tid] = p3;
    __syncthreads();
    for (int off = 1; off < 256; off <<= 1) {
        int t = (tid >= off) ? s[tid - off] : 0;
        __syncthreads();
        s[tid] += t;
        __syncthreads();
    }
    if (tid == 255) base_s = atomicAdd(gbase, s[255]);
    int excl = s[tid] - p3;
    __syncthreads();
    int e0 = base_s + excl;
    int e1 = e0 + v.x, e2 = e1 + v.y, e3 = e2 + v.z;
    if (i + 0 < N_NODES) { start[i + 0] = e0; cursor[i + 0] = e0; }
    if (i + 1 < N_NODES) { start[i + 1] = e1; cursor[i + 1] = e1; }
    if (i + 2 < N_NODES) { start[i + 2] = e2; cursor[i + 2] = e2; }
    if (i + 3 < N_NODES) { start[i + 3] = e3; cursor[i + 3] = e3; }
}

__global__ __launch_bounds__(256) void build_csr(const int* __restrict__ ei,
                                                 int* __restrict__ cursor,
                                                 int* __restrict__ csr_src)
{
    int e = blockIdx.x * 256 + threadIdx.x;
    if (e >= N_EDGES) return;
    int d = ei[N_EDGES + e];
    int pos = atomicAdd(&cursor[d], 1);
    csr_src[pos] = ei[e];
}

// ---------------------------------------------------------------------------
// mid: fused gather1(+bias+right+relu) -> LDS h-tile (32 nodes) -> gemm2 MFMA
// ---------------------------------------------------------------------------
__global__ __launch_bounds__(256) void mid(
    const unsigned short* __restrict__ xl,
    const unsigned short* __restrict__ xr,
    const int* __restrict__ start,
    const int* __restrict__ deg,
    const int* __restrict__ csr_src,
    const float* __restrict__ b1l,
    const unsigned short* __restrict__ wbf2,   // [64][64] bf16
    unsigned short* __restrict__ hl,
    unsigned short* __restrict__ hr)
{
    __shared__ unsigned short hs[32 * 64];     // 4KB, swizzled rows of 128B

    const int tid = threadIdx.x;
    const int nd  = tid >> 3;                  // local node 0..31
    const int q   = tid & 7;                   // feat chunk 0..7
    const int node = blockIdx.x * 32 + nd;     // always < N_NODES

    const int beg = start[node];
    const int dg  = deg[node];

    float acc[8] = {0.f,0.f,0.f,0.f,0.f,0.f,0.f,0.f};
    for (int i = 0; i < dg; ++i) {
        int s = csr_src[beg + i];
        u16x8 v = *(const u16x8*)&xl[s * 64 + 8 * q];
        #pragma unroll
        for (int j = 0; j < 8; ++j) acc[j] += bf2f(v[j]);
    }
    const float inv = 1.0f / (float)max(dg, 1);
    u16x8 rv = *(const u16x8*)&xr[node * 64 + 8 * q];
    float4 b0 = *(const float4*)&b1l[8 * q];
    float4 b1 = *(const float4*)&b1l[8 * q + 4];
    float bb[8] = {b0.x,b0.y,b0.z,b0.w,b1.x,b1.y,b1.z,b1.w};
    u16x8 hv;
    #pragma unroll
    for (int j = 0; j < 8; ++j) {
        float o = fmaf(acc[j], inv, bb[j]) + bf2f(rv[j]);
        hv[j] = f2bf(fmaxf(o, 0.f));
    }
    *(u16x8*)((char*)hs + nd * 128 + ((q * 16) ^ ((nd & 7) << 4))) = hv;
    __syncthreads();

    // gemm2: wave wv handles feat tile wv*16; B = h nodes from LDS
    const int wv   = tid >> 6;
    const int l    = tid & 63;
    const int lrow = l & 15;
    const int hi   = l >> 4;

    f32x4 a0 = (f32x4){0.f,0.f,0.f,0.f};
    f32x4 a1 = (f32x4){0.f,0.f,0.f,0.f};
    #pragma unroll
    for (int kt = 0; kt < 2; ++kt) {
        const int kin = kt * 64 + hi * 16;     // k byte offset within row
        bf16x8 bf0 = __builtin_bit_cast(bf16x8, *(const u16x8*)
            ((const char*)hs + lrow * 128 + (kin ^ ((lrow & 7) << 4))));
        bf16x8 bf1 = __builtin_bit_cast(bf16x8, *(const u16x8*)
            ((const char*)hs + (16 + lrow) * 128 + (kin ^ ((lrow & 7) << 4))));
        bf16x8 a = ldfrag_bf16(wbf2 + (wv * 16 + lrow) * 64 + kt * 32 + hi * 8);
        a0 = __builtin_amdgcn_mfma_f32_16x16x32_bf16(a, bf0, a0, 0, 0, 0);
        a1 = __builtin_amdgcn_mfma_f32_16x16x32_bf16(a, bf1, a1, 0, 0, 0);
    }

    const int n0 = blockIdx.x * 32 + lrow;
    const int n1 = n0 + 16;
    const int feat = wv * 16 + hi * 4;
    u16x4 p0, p1;
    p0[0]=f2bf(a0[0]); p0[1]=f2bf(a0[1]); p0[2]=f2bf(a0[2]); p0[3]=f2bf(a0[3]);
    p1[0]=f2bf(a1[0]); p1[1]=f2bf(a1[1]); p1[2]=f2bf(a1[2]); p1[3]=f2bf(a1[3]);
    if (wv < 2) {
        *(u16x4*)&hl[n0 * 32 + feat] = p0;
        *(u16x4*)&hl[n1 * 32 + feat] = p1;
    } else {
        *(u16x4*)&hr[n0 * 32 + (feat - 32)] = p0;
        *(u16x4*)&hr[n1 * 32 + (feat - 32)] = p1;
    }
}

// ---------------------------------------------------------------------------
// gather2: out[n] = (sum hl[s]) / max(deg,1) + b2 + hr[n]   (f32 out)
// ---------------------------------------------------------------------------
__global__ __launch_bounds__(256) void gather2(
    const unsigned short* __restrict__ hl,
    const int* __restrict__ start,
    const int* __restrict__ deg,
    const int* __restrict__ csr_src,
    const float* __restrict__ b2l,
    const unsigned short* __restrict__ hr,
    float* __restrict__ out)
{
    int t = blockIdx.x * 256 + threadIdx.x;
    int n = t >> 2;
    int q = t & 3;
    if (n >= N_NODES) return;
    int beg = start[n], dg = deg[n];

    float acc[8] = {0.f,0.f,0.f,0.f,0.f,0.f,0.f,0.f};
    for (int i = 0; i < dg; ++i) {
        int s = csr_src[beg + i];
        u16x8 v = *(const u16x8*)&hl[s * 32 + 8 * q];
        #pragma unroll
        for (int j = 0; j < 8; ++j) acc[j] += bf2f(v[j]);
    }
    float inv = 1.0f / (float)max(dg, 1);
    u16x8 rv = *(const u16x8*)&hr[n * 32 + 8 * q];
    float4 b0 = *(const float4*)&b2l[8 * q];
    float4 b1 = *(const float4*)&b2l[8 * q + 4];
    float bb[8] = {b0.x,b0.y,b0.z,b0.w,b1.x,b1.y,b1.z,b1.w};
    float o[8];
    #pragma unroll
    for (int j = 0; j < 8; ++j)
        o[j] = fmaf(acc[j], inv, bb[j]) + bf2f(rv[j]);
    float* op = out + n * 32 + 8 * q;
    *(float4*)op       = make_float4(o[0], o[1], o[2], o[3]);
    *(float4*)(op + 4) = make_float4(o[4], o[5], o[6], o[7]);
}

extern "C" void kernel_launch(void* const* d_in, const int* in_sizes, int n_in,
                              void* d_out, int out_size, void* d_ws, size_t ws_size,
                              hipStream_t stream)
{
    const float* x   = (const float*)d_in[0];
    const int*   ei  = (const int*)d_in[1];   // int32 (JAX x64 disabled)
    const float* w1l = (const float*)d_in[2];
    const float* b1l = (const float*)d_in[3];
    const float* w1r = (const float*)d_in[4];
    const float* w2l = (const float*)d_in[5];
    const float* b2l = (const float*)d_in[6];
    const float* w2r = (const float*)d_in[7];
    float* out = (float*)d_out;

    char* ws = (char*)d_ws;
    unsigned short* xl   = (unsigned short*)(ws + 0);          // 100000x64 bf16
    unsigned short* xr   = (unsigned short*)(ws + 12800000);
    unsigned short* hl   = (unsigned short*)(ws + 25600000);   // 100000x32 bf16
    unsigned short* hr   = (unsigned short*)(ws + 32000000);
    int*   csr_src = (int*)(ws + 38400000);                    // 2.4MB
    int*   deg     = (int*)(ws + 40800000);                    // N_PAD
    int*   start   = (int*)(ws + 41201408);
    int*   cursor  = (int*)(ws + 41601408);
    unsigned short* wbf1 = (unsigned short*)(ws + 42001408);   // [128][128]
    unsigned short* wbf2 = (unsigned short*)(ws + 42034176);   // [64][64]
    int*   gbase   = (int*)(ws + 42042368);

    // 1. prep: zero deg/gbase + convert weights
    prep<<<392, 256, 0, stream>>>(w1l, w1r, w2l, w2r, wbf1, wbf2, deg, gbase);
    // 2. front: layer-1 GEMM + degree histogram (independent, merged)
    front<<<G1_BLOCKS + HIST_BLOCKS, 256, 0, stream>>>(x, wbf1, ei, xl, xr, deg);
    // 3. scan (atomic block base)
    scan_atomic<<<NB1, 256, 0, stream>>>(deg, gbase, start, cursor);
    // 4. bucket edges
    build_csr<<<HIST_BLOCKS, 256, 0, stream>>>(ei, cursor, csr_src);
    // 5. fused gather1 + epilogue + gemm2 (h stays in LDS)
    mid<<<MID_BLOCKS, 256, 0, stream>>>(xl, xr, start, deg, csr_src, b1l, wbf2, hl, hr);
    // 6. gather2 + epilogue -> out
    gather2<<<(N_NODES * 4 + 255) / 256, 256, 0, stream>>>(hl, start, deg, csr_src, b2l, hr, out);
}

// Round 8
// 129.562 us; speedup vs baseline: 1.0540x; 1.0540x over previous
//
#include <hip/hip_runtime.h>

#define N_NODES 100000
#define N_EDGES 600000
#define N_PAD   100352      // N_NODES rounded to 1024 (scan tiles)
#define NB1     98          // N_PAD / 1024
#define G1_BLOCKS 3125      // N_NODES / 32 exactly
#define HIST_BLOCKS 2344    // ceil(600000/256)
#define MID_BLOCKS 3125     // N_NODES / 32 exactly

typedef __bf16 bf16x8 __attribute__((ext_vector_type(8)));
typedef float  f32x4  __attribute__((ext_vector_type(4)));
typedef unsigned short u16x8 __attribute__((ext_vector_type(8)));
typedef unsigned short u16x4 __attribute__((ext_vector_type(4)));

__device__ inline unsigned short f2bf(float f) {
    __bf16 h = (__bf16)f;
    return __builtin_bit_cast(unsigned short, h);
}
__device__ inline float bf2f(unsigned short u) {
    return __builtin_bit_cast(float, ((unsigned)u) << 16);
}
__device__ inline bf16x8 ldfrag_bf16(const unsigned short* p) {
    u16x8 v = *(const u16x8*)p;
    return __builtin_bit_cast(bf16x8, v);
}

// ---------------------------------------------------------------------------
// prep: zero deg + gbase, convert W1 ([128][128]) and W2 ([64][64]) to bf16
// ---------------------------------------------------------------------------
__global__ __launch_bounds__(256) void prep(
    const float* __restrict__ w1l, const float* __restrict__ w1r,
    const float* __restrict__ w2l, const float* __restrict__ w2r,
    unsigned short* __restrict__ wbf1, unsigned short* __restrict__ wbf2,
    int* __restrict__ deg, int* __restrict__ gbase)
{
    int i = blockIdx.x * 256 + threadIdx.x;
    if (i < N_PAD) deg[i] = 0;
    if (i == 0) gbase[0] = 0;
    if (i < 16384) {
        int row = i >> 7, k = i & 127;
        float v = (row < 64) ? w1l[(row << 7) + k] : w1r[((row - 64) << 7) + k];
        wbf1[i] = f2bf(v);
    } else if (i < 20480) {
        int j = i - 16384;
        int row = j >> 6, k = j & 63;
        float v = (row < 32) ? w2l[(row << 6) + k] : w2r[((row - 32) << 6) + k];
        wbf2[j] = f2bf(v);
    }
}

// ---------------------------------------------------------------------------
// front: blocks [0, G1_BLOCKS) = layer-1 GEMM via 8KB swizzled bf16 LDS tile
//        (32 nodes/block, coalesced staging, cvt at stage time);
//        blocks [G1_BLOCKS, +HIST_BLOCKS) = degree histogram.
// ---------------------------------------------------------------------------
__global__ __launch_bounds__(256) void front(
    const float* __restrict__ x,
    const unsigned short* __restrict__ wbf1,   // [128][128] bf16
    const int* __restrict__ ei,
    unsigned short* __restrict__ xl,
    unsigned short* __restrict__ xr,
    int* __restrict__ deg)
{
    const int b   = blockIdx.x;
    const int tid = threadIdx.x;

    if (b >= G1_BLOCKS) {
        int e = (b - G1_BLOCKS) * 256 + tid;
        if (e < N_EDGES) atomicAdd(&deg[ei[N_EDGES + e]], 1);
        return;
    }

    __shared__ unsigned short xs[32 * 128];    // 8KB bf16, XOR-swizzled rows of 256B
    const int nbase = b * 32;                  // exact: 100000 = 3125*32

    // ---- stage x-tile: 2 rounds x 16B(bf16)/thread, dense global reads ----
    #pragma unroll
    for (int j = 0; j < 2; ++j) {
        const int L   = j * 4096 + tid * 16;   // linear byte offset in bf16 tile
        const int row = L >> 8;                // local node 0..31
        const int off = L & 255;               // byte within 256B row
        const float* src = x + (size_t)(nbase + row) * 128 + (off >> 1);
        float4 u = *(const float4*)src;
        float4 w = *(const float4*)(src + 4);
        u16x8 o;
        o[0]=f2bf(u.x); o[1]=f2bf(u.y); o[2]=f2bf(u.z); o[3]=f2bf(u.w);
        o[4]=f2bf(w.x); o[5]=f2bf(w.y); o[6]=f2bf(w.z); o[7]=f2bf(w.w);
        *(u16x8*)((char*)xs + row * 256 + (off ^ ((row & 7) << 4))) = o;
    }
    __syncthreads();

    // ---- MFMA: wave wv owns feats [wv*32, wv*32+32), all 32 nodes ----
    const int wv   = tid >> 6;
    const int l    = tid & 63;
    const int lrow = l & 15;
    const int hi   = l >> 4;

    f32x4 acc[2][2];                           // [ntile][ftile]
    #pragma unroll
    for (int nt = 0; nt < 2; ++nt)
        #pragma unroll
        for (int ft = 0; ft < 2; ++ft) acc[nt][ft] = (f32x4){0.f,0.f,0.f,0.f};

    #pragma unroll
    for (int kt = 0; kt < 4; ++kt) {
        const int koff = kt * 64 + hi * 16;    // byte offset of lane's 8 bf16
        const int r0 = lrow, r1 = 16 + lrow;
        bf16x8 b0 = __builtin_bit_cast(bf16x8, *(const u16x8*)
            ((const char*)xs + r0 * 256 + (koff ^ ((r0 & 7) << 4))));
        bf16x8 b1 = __builtin_bit_cast(bf16x8, *(const u16x8*)
            ((const char*)xs + r1 * 256 + (koff ^ ((r1 & 7) << 4))));
        #pragma unroll
        for (int ft = 0; ft < 2; ++ft) {
            const int frow = wv * 32 + ft * 16 + lrow;
            bf16x8 a = ldfrag_bf16(wbf1 + frow * 128 + kt * 32 + hi * 8);  // L1-resident
            acc[0][ft] = __builtin_amdgcn_mfma_f32_16x16x32_bf16(a, b0, acc[0][ft], 0, 0, 0);
            acc[1][ft] = __builtin_amdgcn_mfma_f32_16x16x32_bf16(a, b1, acc[1][ft], 0, 0, 0);
        }
    }

    // ---- D: col = lane&15 -> node, row = hi*4 + r -> feat ----
    #pragma unroll
    for (int nt = 0; nt < 2; ++nt) {
        const int node = nbase + nt * 16 + lrow;
        #pragma unroll
        for (int ft = 0; ft < 2; ++ft) {
            const int feat = wv * 32 + ft * 16 + hi * 4;
            u16x4 p;
            p[0] = f2bf(acc[nt][ft][0]); p[1] = f2bf(acc[nt][ft][1]);
            p[2] = f2bf(acc[nt][ft][2]); p[3] = f2bf(acc[nt][ft][3]);
            if (wv < 2) *(u16x4*)&xl[node * 64 + feat]        = p;
            else        *(u16x4*)&xr[node * 64 + (feat - 64)] = p;
        }
    }
}

// ---------------------------------------------------------------------------
// scan: per-block scan of deg + atomic global base -> start[], cursor[]
// ---------------------------------------------------------------------------
__global__ __launch_bounds__(256) void scan_atomic(
    const int* __restrict__ deg, int* __restrict__ gbase,
    int* __restrict__ start, int* __restrict__ cursor)
{
    __shared__ int s[256];
    __shared__ int base_s;
    int b = blockIdx.x, tid = threadIdx.x;
    int i = b * 1024 + tid * 4;
    int4 v = *(const int4*)&deg[i];
    int p0 = v.x, p1 = p0 + v.y, p2 = p1 + v.z, p3 = p2 + v.w;
    s[tid] = p3;
    __syncthreads();
    for (int off = 1; off < 256; off <<= 1) {
        int t = (tid >= off) ? s[tid - off] : 0;
        __syncthreads();
        s[tid] += t;
        __syncthreads();
    }
    if (tid == 255) base_s = atomicAdd(gbase, s[255]);
    int excl = s[tid] - p3;
    __syncthreads();
    int e0 = base_s + excl;
    int e1 = e0 + v.x, e2 = e1 + v.y, e3 = e2 + v.z;
    if (i + 0 < N_NODES) { start[i + 0] = e0; cursor[i + 0] = e0; }
    if (i + 1 < N_NODES) { start[i + 1] = e1; cursor[i + 1] = e1; }
    if (i + 2 < N_NODES) { start[i + 2] = e2; cursor[i + 2] = e2; }
    if (i + 3 < N_NODES) { start[i + 3] = e3; cursor[i + 3] = e3; }
}

__global__ __launch_bounds__(256) void build_csr(const int* __restrict__ ei,
                                                 int* __restrict__ cursor,
                                                 int* __restrict__ csr_src)
{
    int e = blockIdx.x * 256 + threadIdx.x;
    if (e >= N_EDGES) return;
    int d = ei[N_EDGES + e];
    int pos = atomicAdd(&cursor[d], 1);
    csr_src[pos] = ei[e];
}

// ---------------------------------------------------------------------------
// mid: fused gather1(+bias+right+relu) -> LDS h-tile (32 nodes) -> gemm2 MFMA
// ---------------------------------------------------------------------------
__global__ __launch_bounds__(256) void mid(
    const unsigned short* __restrict__ xl,
    const unsigned short* __restrict__ xr,
    const int* __restrict__ start,
    const int* __restrict__ deg,
    const int* __restrict__ csr_src,
    const float* __restrict__ b1l,
    const unsigned short* __restrict__ wbf2,   // [64][64] bf16
    unsigned short* __restrict__ hl,
    unsigned short* __restrict__ hr)
{
    __shared__ unsigned short hs[32 * 64];     // 4KB, swizzled rows of 128B

    const int tid = threadIdx.x;
    const int nd  = tid >> 3;                  // local node 0..31
    const int q   = tid & 7;                   // feat chunk 0..7
    const int node = blockIdx.x * 32 + nd;     // always < N_NODES

    const int beg = start[node];
    const int dg  = deg[node];

    float acc[8] = {0.f,0.f,0.f,0.f,0.f,0.f,0.f,0.f};
    for (int i = 0; i < dg; ++i) {
        int s = csr_src[beg + i];
        u16x8 v = *(const u16x8*)&xl[s * 64 + 8 * q];
        #pragma unroll
        for (int j = 0; j < 8; ++j) acc[j] += bf2f(v[j]);
    }
    const float inv = 1.0f / (float)max(dg, 1);
    u16x8 rv = *(const u16x8*)&xr[node * 64 + 8 * q];
    float4 b0 = *(const float4*)&b1l[8 * q];
    float4 b1 = *(const float4*)&b1l[8 * q + 4];
    float bb[8] = {b0.x,b0.y,b0.z,b0.w,b1.x,b1.y,b1.z,b1.w};
    u16x8 hv;
    #pragma unroll
    for (int j = 0; j < 8; ++j) {
        float o = fmaf(acc[j], inv, bb[j]) + bf2f(rv[j]);
        hv[j] = f2bf(fmaxf(o, 0.f));
    }
    *(u16x8*)((char*)hs + nd * 128 + ((q * 16) ^ ((nd & 7) << 4))) = hv;
    __syncthreads();

    // gemm2: wave wv handles feat tile wv*16; B = h nodes from LDS
    const int wv   = tid >> 6;
    const int l    = tid & 63;
    const int lrow = l & 15;
    const int hi   = l >> 4;

    f32x4 a0 = (f32x4){0.f,0.f,0.f,0.f};
    f32x4 a1 = (f32x4){0.f,0.f,0.f,0.f};
    #pragma unroll
    for (int kt = 0; kt < 2; ++kt) {
        const int kin = kt * 64 + hi * 16;     // k byte offset within row
        bf16x8 bf0 = __builtin_bit_cast(bf16x8, *(const u16x8*)
            ((const char*)hs + lrow * 128 + (kin ^ ((lrow & 7) << 4))));
        bf16x8 bf1 = __builtin_bit_cast(bf16x8, *(const u16x8*)
            ((const char*)hs + (16 + lrow) * 128 + (kin ^ ((lrow & 7) << 4))));
        bf16x8 a = ldfrag_bf16(wbf2 + (wv * 16 + lrow) * 64 + kt * 32 + hi * 8);
        a0 = __builtin_amdgcn_mfma_f32_16x16x32_bf16(a, bf0, a0, 0, 0, 0);
        a1 = __builtin_amdgcn_mfma_f32_16x16x32_bf16(a, bf1, a1, 0, 0, 0);
    }

    const int n0 = blockIdx.x * 32 + lrow;
    const int n1 = n0 + 16;
    const int feat = wv * 16 + hi * 4;
    u16x4 p0, p1;
    p0[0]=f2bf(a0[0]); p0[1]=f2bf(a0[1]); p0[2]=f2bf(a0[2]); p0[3]=f2bf(a0[3]);
    p1[0]=f2bf(a1[0]); p1[1]=f2bf(a1[1]); p1[2]=f2bf(a1[2]); p1[3]=f2bf(a1[3]);
    if (wv < 2) {
        *(u16x4*)&hl[n0 * 32 + feat] = p0;
        *(u16x4*)&hl[n1 * 32 + feat] = p1;
    } else {
        *(u16x4*)&hr[n0 * 32 + (feat - 32)] = p0;
        *(u16x4*)&hr[n1 * 32 + (feat - 32)] = p1;
    }
}

// ---------------------------------------------------------------------------
// gather2: out[n] = (sum hl[s]) / max(deg,1) + b2 + hr[n]   (f32 out)
// ---------------------------------------------------------------------------
__global__ __launch_bounds__(256) void gather2(
    const unsigned short* __restrict__ hl,
    const int* __restrict__ start,
    const int* __restrict__ deg,
    const int* __restrict__ csr_src,
    const float* __restrict__ b2l,
    const unsigned short* __restrict__ hr,
    float* __restrict__ out)
{
    int t = blockIdx.x * 256 + threadIdx.x;
    int n = t >> 2;
    int q = t & 3;
    if (n >= N_NODES) return;
    int beg = start[n], dg = deg[n];

    float acc[8] = {0.f,0.f,0.f,0.f,0.f,0.f,0.f,0.f};
    for (int i = 0; i < dg; ++i) {
        int s = csr_src[beg + i];
        u16x8 v = *(const u16x8*)&hl[s * 32 + 8 * q];
        #pragma unroll
        for (int j = 0; j < 8; ++j) acc[j] += bf2f(v[j]);
    }
    float inv = 1.0f / (float)max(dg, 1);
    u16x8 rv = *(const u16x8*)&hr[n * 32 + 8 * q];
    float4 b0 = *(const float4*)&b2l[8 * q];
    float4 b1 = *(const float4*)&b2l[8 * q + 4];
    float bb[8] = {b0.x,b0.y,b0.z,b0.w,b1.x,b1.y,b1.z,b1.w};
    float o[8];
    #pragma unroll
    for (int j = 0; j < 8; ++j)
        o[j] = fmaf(acc[j], inv, bb[j]) + bf2f(rv[j]);
    float* op = out + n * 32 + 8 * q;
    *(float4*)op       = make_float4(o[0], o[1], o[2], o[3]);
    *(float4*)(op + 4) = make_float4(o[4], o[5], o[6], o[7]);
}

extern "C" void kernel_launch(void* const* d_in, const int* in_sizes, int n_in,
                              void* d_out, int out_size, void* d_ws, size_t ws_size,
                              hipStream_t stream)
{
    const float* x   = (const float*)d_in[0];
    const int*   ei  = (const int*)d_in[1];   // int32 (JAX x64 disabled)
    const float* w1l = (const float*)d_in[2];
    const float* b1l = (const float*)d_in[3];
    const float* w1r = (const float*)d_in[4];
    const float* w2l = (const float*)d_in[5];
    const float* b2l = (const float*)d_in[6];
    const float* w2r = (const float*)d_in[7];
    float* out = (float*)d_out;

    char* ws = (char*)d_ws;
    unsigned short* xl   = (unsigned short*)(ws + 0);          // 100000x64 bf16
    unsigned short* xr   = (unsigned short*)(ws + 12800000);
    unsigned short* hl   = (unsigned short*)(ws + 25600000);   // 100000x32 bf16
    unsigned short* hr   = (unsigned short*)(ws + 32000000);
    int*   csr_src = (int*)(ws + 38400000);                    // 2.4MB
    int*   deg     = (int*)(ws + 40800000);                    // N_PAD
    int*   start   = (int*)(ws + 41201408);
    int*   cursor  = (int*)(ws + 41601408);
    unsigned short* wbf1 = (unsigned short*)(ws + 42001408);   // [128][128]
    unsigned short* wbf2 = (unsigned short*)(ws + 42034176);   // [64][64]
    int*   gbase   = (int*)(ws + 42042368);

    // 1. prep: zero deg/gbase + convert weights
    prep<<<392, 256, 0, stream>>>(w1l, w1r, w2l, w2r, wbf1, wbf2, deg, gbase);
    // 2. front: layer-1 GEMM (LDS-staged) + degree histogram (merged)
    front<<<G1_BLOCKS + HIST_BLOCKS, 256, 0, stream>>>(x, wbf1, ei, xl, xr, deg);
    // 3. scan (atomic block base)
    scan_atomic<<<NB1, 256, 0, stream>>>(deg, gbase, start, cursor);
    // 4. bucket edges
    build_csr<<<HIST_BLOCKS, 256, 0, stream>>>(ei, cursor, csr_src);
    // 5. fused gather1 + epilogue + gemm2 (h stays in LDS)
    mid<<<MID_BLOCKS, 256, 0, stream>>>(xl, xr, start, deg, csr_src, b1l, wbf2, hl, hr);
    // 6. gather2 + epilogue -> out
    gather2<<<(N_NODES * 4 + 255) / 256, 256, 0, stream>>>(hl, start, deg, csr_src, b2l, hr, out);
}